// Round 4
// baseline (74.925 us; speedup 1.0000x reference)
//
#include <hip/hip_runtime.h>
#include <math.h>

#define WS_AB   16        // float idx: 24*512 accumulated fold vectors
#define WS_CNT  12352     // int counter slot (as float idx)
#define ABS     516       // padded LDS stride
#define NBLK    256

__constant__ float FREQ_BIAS[36] = {
    0.0f, 0.05f, 0.0f, 0.0f, 0.0f, 0.0f,
    0.05f, 0.0f, 0.1f, 0.05f, 0.0f, 0.0f,
    0.0f, 0.1f, 0.0f, 0.1f, 0.0f, 0.0f,
    0.0f, 0.05f, 0.1f, 0.0f, 0.1f, 0.0f,
    0.0f, 0.0f, 0.0f, 0.1f, 0.0f, 0.1f,
    0.0f, 0.0f, 0.0f, 0.0f, 0.1f, 0.0f
};

__global__ __launch_bounds__(256) void kfused(
    const float* __restrict__ x,
    const float* __restrict__ W_in, const float* __restrict__ b_in,
    const float* __restrict__ Wq, const float* __restrict__ bq,
    const float* __restrict__ Wk, const float* __restrict__ bk,
    const float* __restrict__ Wv, const float* __restrict__ bv,
    const float* __restrict__ Wo, const float* __restrict__ bo,
    const float* __restrict__ gamma, const float* __restrict__ beta,
    float* __restrict__ ws, float* __restrict__ out, int total)
{
    __shared__ union {
        struct { float ls[8][512]; float partial[4][8][64]; } p1;  // 24.5 KB
        struct { float AB[24 * ABS]; float T[576]; } p2;           // 51.8 KB
    } U;
    __shared__ float red[13][4];
    __shared__ float stats_s[13];

    const int tid = threadIdx.x;
    const int wave = tid >> 6, lane = tid & 63;
    const int bid = blockIdx.x;

    // ---------- phase 0: LN stats + folded vectors (every block, local) ----------
    const float k_ln = 0.0179889457300305367f;  // ln(10000)/512
    const float freqs[6] = {0.2f, 0.4f, 0.6f, 0.8f, 1.0f, 0.0f};
    float wd[2], cc2[2][6], gm[2], bt[2];
    #pragma unroll
    for (int q = 0; q < 2; ++q) {
        const int d = tid + q * 256;
        wd[q] = W_in[d];
        gm[q] = gamma[d];
        bt[q] = beta[d];
        float dv = expf(-(float)(d & ~1) * k_ln);
        float bi = b_in[d];
        bool odd = (d & 1);
        #pragma unroll
        for (int s = 0; s < 6; ++s) {
            float ph = freqs[s] * dv;
            cc2[q][s] = bi + (odd ? cosf(ph) : sinf(ph));
        }
    }
    // means
    {
        float sums[7];
        sums[0] = wd[0] + wd[1];
        #pragma unroll
        for (int s = 0; s < 6; ++s) sums[1 + s] = cc2[0][s] + cc2[1][s];
        #pragma unroll
        for (int m = 1; m < 64; m <<= 1) {
            #pragma unroll
            for (int k = 0; k < 7; ++k) sums[k] += __shfl_xor(sums[k], m, 64);
        }
        if (lane == 0) {
            #pragma unroll
            for (int k = 0; k < 7; ++k) red[k][wave] = sums[k];
        }
    }
    __syncthreads();
    float mw, mc[6];
    mw = (red[0][0] + red[0][1] + red[0][2] + red[0][3]) * (1.0f / 512.0f);
    #pragma unroll
    for (int s = 0; s < 6; ++s)
        mc[s] = (red[1 + s][0] + red[1 + s][1] + red[1 + s][2] + red[1 + s][3]) * (1.0f / 512.0f);
    __syncthreads();

    float hw[2], hc[2][6];
    #pragma unroll
    for (int q = 0; q < 2; ++q) {
        hw[q] = wd[q] - mw;
        #pragma unroll
        for (int s = 0; s < 6; ++s) hc[q][s] = cc2[q][s] - mc[s];
    }
    {
        float moms[13];
        moms[0] = hw[0] * hw[0] + hw[1] * hw[1];
        #pragma unroll
        for (int s = 0; s < 6; ++s) {
            moms[1 + s] = hw[0] * hc[0][s] + hw[1] * hc[1][s];
            moms[7 + s] = hc[0][s] * hc[0][s] + hc[1][s] * hc[1][s];
        }
        #pragma unroll
        for (int m = 1; m < 64; m <<= 1) {
            #pragma unroll
            for (int k = 0; k < 13; ++k) moms[k] += __shfl_xor(moms[k], m, 64);
        }
        if (lane == 0) {
            #pragma unroll
            for (int k = 0; k < 13; ++k) red[k][wave] = moms[k];
        }
    }
    // folded vectors into LDS
    #pragma unroll
    for (int q = 0; q < 2; ++q) {
        const int d = tid + q * 256;
        U.p1.ls[0][d] = hw[q] * gm[q];
        #pragma unroll
        for (int s = 0; s < 6; ++s) U.p1.ls[1 + s][d] = hc[q][s] * gm[q];
        U.p1.ls[7][d] = bt[q];
    }
    __syncthreads();
    if (tid < 13)
        stats_s[tid] = (red[tid][0] + red[tid][1] + red[tid][2] + red[tid][3]) * (1.0f / 512.0f);

    // ---------- phase 1: matvec (blocks 0..191) ----------
    if (bid < 192) {
        const int p = bid >> 6, cg = (bid >> 3) & 7, rc = bid & 7;
        const float* W = (p == 0) ? Wq : ((p == 1) ? Wk : Wv);
        const int col = (cg << 6) | lane;
        const int row0 = (rc << 6) | (wave << 4);
        float acc[8] = {0.f, 0.f, 0.f, 0.f, 0.f, 0.f, 0.f, 0.f};
        #pragma unroll
        for (int rr = 0; rr < 16; ++rr) {
            const int row = row0 + rr;
            const float wv = W[row * 512 + col];
            #pragma unroll
            for (int v = 0; v < 8; ++v) acc[v] = fmaf(wv, U.p1.ls[v][row], acc[v]);
        }
        #pragma unroll
        for (int v = 0; v < 8; ++v) U.p1.partial[wave][v][lane] = acc[v];
        __syncthreads();
        const float* bb = (p == 0) ? bq : ((p == 1) ? bk : bv);
        #pragma unroll
        for (int ii = 0; ii < 2; ++ii) {
            const int idx = tid + ii * 256;
            const int v = idx >> 6, cx = idx & 63;
            float t = U.p1.partial[0][v][cx] + U.p1.partial[1][v][cx]
                    + U.p1.partial[2][v][cx] + U.p1.partial[3][v][cx];
            if (v == 7 && rc == 0) t += bb[(cg << 6) | cx];
            atomicAdd(&ws[WS_AB + (((p << 3) | v) << 9) + ((cg << 6) | cx)], t);
        }
    }

    // ---------- grid barrier ----------
    __threadfence();
    __syncthreads();
    if (tid == 0) {
        int* cnt = (int*)ws + WS_CNT;
        atomicAdd(cnt, 1);
        while (__hip_atomic_load(cnt, __ATOMIC_RELAXED, __HIP_MEMORY_SCOPE_AGENT) < NBLK)
            __builtin_amdgcn_s_sleep(2);
    }
    __syncthreads();
    __threadfence();

    // ---------- phase 2: stage AB + dot tables ----------
    for (int e = tid; e < 24 * 512; e += 256) {
        U.p2.AB[((e >> 9) * ABS) + (e & 511)] =
            __hip_atomic_load(&ws[WS_AB + e], __ATOMIC_RELAXED, __HIP_MEMORY_SCOPE_AGENT);
    }
    __syncthreads();
    #pragma unroll
    for (int ee = 0; ee < 2; ++ee) {
        const int e = tid + ee * 256;
        const int h = e >> 6, a = (e >> 3) & 7, b2 = e & 7;
        const float* qv = &U.p2.AB[a * ABS + h * 64];
        const float* kv = &U.p2.AB[(8 + b2) * ABS + h * 64];
        float acc = 0.f;
        #pragma unroll
        for (int c = 0; c < 64; ++c) acc = fmaf(qv[c], kv[c], acc);
        U.p2.T[e] = acc * 0.125f;   // fold hd^-0.5
    }
    if (tid < 64) {
        const int h = tid >> 3, a = tid & 7;
        const float* vv = &U.p2.AB[(16 + a) * ABS + h * 64];
        const float* wo = Wo + h * 64;
        float acc = 0.f;
        #pragma unroll
        for (int c = 0; c < 64; ++c) acc = fmaf(vv[c], wo[c], acc);
        U.p2.T[512 + tid] = acc;
    }
    __syncthreads();

    // ---------- phase 3: main attention, grid-stride x2 ----------
    const float vw = stats_s[0];
    const float* cov = stats_s + 1;
    const float* vc = stats_s + 7;
    const float bo0 = bo[0];
    const float* D8 = U.p2.T;
    const float* VD = U.p2.T + 512;

    for (int it = 0; it < 2; ++it) {
        const int g = (it * NBLK + bid) * 256 + tid;
        if (g >= total) break;
        const unsigned b = (unsigned)g / 6u;
        const int i = g - (int)b * 6;

        const float2* xp = (const float2*)(x + (size_t)b * 6u);
        const float2 x01 = xp[0], x23 = xp[1], x45 = xp[2];
        const float al[6] = {x01.x, x01.y, x23.x, x23.y, x45.x, x45.y};

        float r[6], u[6];
        #pragma unroll
        for (int j = 0; j < 6; ++j) {
            float a = al[j];
            float var = fmaf(a, fmaf(a, vw, 2.0f * cov[j]), vc[j]) + 1e-5f;
            r[j] = rsqrtf(var);
            u[j] = a * r[j];
        }

        float bias[6];
        #pragma unroll
        for (int j = 0; j < 6; ++j) bias[j] = FREQ_BIAS[i * 6 + j];

        const float r_i = r[i], u_i = u[i];
        float acc = 0.f;
        float am[6] = {0.f, 0.f, 0.f, 0.f, 0.f, 0.f};

        #pragma unroll
        for (int h = 0; h < 8; ++h) {
            const float* Dh = D8 + h * 64;
            const float* Vh = VD + h * 8;
            const float P1 = Dh[0], P5 = Dh[7], P7 = Dh[56], P9 = Dh[63];
            const float P3i = Dh[(1 + i) * 8], P6i = Dh[(1 + i) * 8 + 7];

            float s[6];
            #pragma unroll
            for (int j = 0; j < 6; ++j) {
                float t1 = fmaf(u[j], P1, fmaf(r[j], Dh[1 + j], P5));
                float t2 = fmaf(u[j], P3i, fmaf(r[j], Dh[(1 + i) * 8 + 1 + j], P6i));
                float t3 = fmaf(u[j], P7, fmaf(r[j], Dh[57 + j], P9));
                s[j] = fmaf(u_i, t1, fmaf(r_i, t2, t3)) + bias[j];
            }
            float m = s[0];
            #pragma unroll
            for (int j = 1; j < 6; ++j) m = fmaxf(m, s[j]);
            float e[6], ssum = 0.f;
            #pragma unroll
            for (int j = 0; j < 6; ++j) { e[j] = __expf(s[j] - m); ssum += e[j]; }
            const float inv = 1.0f / ssum;

            const float av = Vh[0], cvv = Vh[7];
            float ha = 0.f;
            #pragma unroll
            for (int j = 0; j < 6; ++j) {
                float a = e[j] * inv;
                am[j] += a;
                float vp = fmaf(u[j], av, r[j] * Vh[1 + j]);
                ha = fmaf(a, vp, ha);
            }
            acc += ha + cvv;
        }

        out[g] = acc + bo0 + al[i];

        float2* amp = (float2*)(out + total + (size_t)g * 6u);
        amp[0] = make_float2(am[0] * 0.125f, am[1] * 0.125f);
        amp[1] = make_float2(am[2] * 0.125f, am[3] * 0.125f);
        amp[2] = make_float2(am[4] * 0.125f, am[5] * 0.125f);
    }
}

extern "C" void kernel_launch(void* const* d_in, const int* in_sizes, int n_in,
                              void* d_out, int out_size, void* d_ws, size_t ws_size,
                              hipStream_t stream) {
    const float* x     = (const float*)d_in[0];
    const float* W_in  = (const float*)d_in[1];
    const float* b_in  = (const float*)d_in[2];
    const float* Wq    = (const float*)d_in[3];
    const float* bq    = (const float*)d_in[4];
    const float* Wk    = (const float*)d_in[5];
    const float* bk    = (const float*)d_in[6];
    const float* Wv    = (const float*)d_in[7];
    const float* bv    = (const float*)d_in[8];
    const float* Wo    = (const float*)d_in[9];
    const float* bo    = (const float*)d_in[10];
    const float* gamma = (const float*)d_in[11];
    const float* beta  = (const float*)d_in[12];
    float* ws  = (float*)d_ws;
    float* out = (float*)d_out;

    const int total = in_sizes[0];  // B*6

    // zero the atomic-accumulation region + grid-barrier counter (graph-safe)
    hipMemsetAsync(ws, 0, (WS_CNT + 16) * sizeof(float), stream);
    kfused<<<NBLK, 256, 0, stream>>>(x, W_in, b_in, Wq, bq, Wk, bk, Wv, bv,
                                     Wo, bo, gamma, beta, ws, out, total);
}

// Round 5
// 37.503 us; speedup vs baseline: 1.9979x; 1.9979x over previous
//
#include <hip/hip_runtime.h>
#include <math.h>

#define NBLK    256
// ws float-index layout
#define WS_AB   0         // 24*512 floats, atomicAdd-accumulated (zeroed per call)
#define WS_CNT1 12288     // int: matvec-done counter (target 192)
#define WS_CNT2 12289     // int: tables-done counter (target 8)
#define WS_T    12304     // 576 floats: D8[8*64] | VD[8*8] (atomic-stored, no zero needed)
// memset covers floats [0, 12290)

__constant__ float FREQ_BIAS[36] = {
    0.0f, 0.05f, 0.0f, 0.0f, 0.0f, 0.0f,
    0.05f, 0.0f, 0.1f, 0.05f, 0.0f, 0.0f,
    0.0f, 0.1f, 0.0f, 0.1f, 0.0f, 0.0f,
    0.0f, 0.05f, 0.1f, 0.0f, 0.1f, 0.0f,
    0.0f, 0.0f, 0.0f, 0.1f, 0.0f, 0.1f,
    0.0f, 0.0f, 0.0f, 0.0f, 0.1f, 0.0f
};

__global__ __launch_bounds__(256) void kfused(
    const float* __restrict__ x,
    const float* __restrict__ W_in, const float* __restrict__ b_in,
    const float* __restrict__ Wq, const float* __restrict__ bq,
    const float* __restrict__ Wk, const float* __restrict__ bk,
    const float* __restrict__ Wv, const float* __restrict__ bv,
    const float* __restrict__ Wo, const float* __restrict__ bo,
    const float* __restrict__ gamma, const float* __restrict__ beta,
    float* __restrict__ ws, float* __restrict__ out, int total)
{
    __shared__ union {
        struct { float ls[8][512]; float partial[4][8][64]; } p1;  // 24 KB
        struct { float abh[24][65]; } p2;                          // 6.1 KB
    } U;
    __shared__ float red[13][4];
    __shared__ float stats_s[13];
    __shared__ float T_s[576];

    const int tid = threadIdx.x;
    const int wave = tid >> 6, lane = tid & 63;
    const int bid = blockIdx.x;
    int* cnt1 = (int*)ws + WS_CNT1;
    int* cnt2 = (int*)ws + WS_CNT2;

    // ---------- phase 0: LN stats + folded vectors (every block, local) ----------
    const float k_ln = 0.0179889457300305367f;  // ln(10000)/512
    const float freqs[6] = {0.2f, 0.4f, 0.6f, 0.8f, 1.0f, 0.0f};
    float wd[2], cc2[2][6], gm[2], bt[2];
    #pragma unroll
    for (int q = 0; q < 2; ++q) {
        const int d = tid + q * 256;
        wd[q] = W_in[d];
        gm[q] = gamma[d];
        bt[q] = beta[d];
        float dv = expf(-(float)(d & ~1) * k_ln);
        float bi = b_in[d];
        bool odd = (d & 1);
        #pragma unroll
        for (int s = 0; s < 6; ++s) {
            float ph = freqs[s] * dv;
            cc2[q][s] = bi + (odd ? cosf(ph) : sinf(ph));
        }
    }
    {
        float sums[7];
        sums[0] = wd[0] + wd[1];
        #pragma unroll
        for (int s = 0; s < 6; ++s) sums[1 + s] = cc2[0][s] + cc2[1][s];
        #pragma unroll
        for (int m = 1; m < 64; m <<= 1) {
            #pragma unroll
            for (int k = 0; k < 7; ++k) sums[k] += __shfl_xor(sums[k], m, 64);
        }
        if (lane == 0) {
            #pragma unroll
            for (int k = 0; k < 7; ++k) red[k][wave] = sums[k];
        }
    }
    __syncthreads();
    float mw, mc[6];
    mw = (red[0][0] + red[0][1] + red[0][2] + red[0][3]) * (1.0f / 512.0f);
    #pragma unroll
    for (int s = 0; s < 6; ++s)
        mc[s] = (red[1 + s][0] + red[1 + s][1] + red[1 + s][2] + red[1 + s][3]) * (1.0f / 512.0f);
    __syncthreads();

    float hw[2], hc[2][6];
    #pragma unroll
    for (int q = 0; q < 2; ++q) {
        hw[q] = wd[q] - mw;
        #pragma unroll
        for (int s = 0; s < 6; ++s) hc[q][s] = cc2[q][s] - mc[s];
    }
    {
        float moms[13];
        moms[0] = hw[0] * hw[0] + hw[1] * hw[1];
        #pragma unroll
        for (int s = 0; s < 6; ++s) {
            moms[1 + s] = hw[0] * hc[0][s] + hw[1] * hc[1][s];
            moms[7 + s] = hc[0][s] * hc[0][s] + hc[1][s] * hc[1][s];
        }
        #pragma unroll
        for (int m = 1; m < 64; m <<= 1) {
            #pragma unroll
            for (int k = 0; k < 13; ++k) moms[k] += __shfl_xor(moms[k], m, 64);
        }
        if (lane == 0) {
            #pragma unroll
            for (int k = 0; k < 13; ++k) red[k][wave] = moms[k];
        }
    }
    #pragma unroll
    for (int q = 0; q < 2; ++q) {
        const int d = tid + q * 256;
        U.p1.ls[0][d] = hw[q] * gm[q];
        #pragma unroll
        for (int s = 0; s < 6; ++s) U.p1.ls[1 + s][d] = hc[q][s] * gm[q];
        U.p1.ls[7][d] = bt[q];
    }
    __syncthreads();
    if (tid < 13)
        stats_s[tid] = (red[tid][0] + red[tid][1] + red[tid][2] + red[tid][3]) * (1.0f / 512.0f);

    // ---------- phase 1: matvec (blocks 0..191), atomicAdd partials ----------
    if (bid < 192) {
        const int p = bid >> 6, cg = (bid >> 3) & 7, rc = bid & 7;
        const float* W = (p == 0) ? Wq : ((p == 1) ? Wk : Wv);
        const int col = (cg << 6) | lane;
        const int row0 = (rc << 6) | (wave << 4);
        float acc[8] = {0.f, 0.f, 0.f, 0.f, 0.f, 0.f, 0.f, 0.f};
        #pragma unroll
        for (int rr = 0; rr < 16; ++rr) {
            const int row = row0 + rr;
            const float wv = W[row * 512 + col];
            #pragma unroll
            for (int v = 0; v < 8; ++v) acc[v] = fmaf(wv, U.p1.ls[v][row], acc[v]);
        }
        #pragma unroll
        for (int v = 0; v < 8; ++v) U.p1.partial[wave][v][lane] = acc[v];
        __syncthreads();
        const float* bb = (p == 0) ? bq : ((p == 1) ? bk : bv);
        #pragma unroll
        for (int ii = 0; ii < 2; ++ii) {
            const int idx = tid + ii * 256;
            const int v = idx >> 6, cx = idx & 63;
            float t = U.p1.partial[0][v][cx] + U.p1.partial[1][v][cx]
                    + U.p1.partial[2][v][cx] + U.p1.partial[3][v][cx];
            if (v == 7 && rc == 0) t += bb[(cg << 6) | cx];
            atomicAdd(&ws[WS_AB + (((p << 3) | v) << 9) + ((cg << 6) | cx)], t);
        }
    }
    // release: per-wave completion of our atomics at the coherence point (no L2 flush)
    asm volatile("s_waitcnt vmcnt(0)" ::: "memory");
    __syncthreads();
    if (bid < 192 && tid == 0)
        __hip_atomic_fetch_add(cnt1, 1, __ATOMIC_RELAXED, __HIP_MEMORY_SCOPE_AGENT);

    // ---------- phase 2: dot tables (blocks 0..7, one per head) ----------
    if (bid < 8) {
        if (tid == 0) {
            while (__hip_atomic_load(cnt1, __ATOMIC_RELAXED, __HIP_MEMORY_SCOPE_AGENT) < 192)
                __builtin_amdgcn_s_sleep(1);
        }
        __syncthreads();
        asm volatile("" ::: "memory");
        const int h = bid;
        // stage this head's AB slice: 24 vecs x 64 cols (6 loads/thread)
        for (int e = tid; e < 24 * 64; e += 256) {
            const int v = e >> 6, c = e & 63;
            U.p2.abh[v][c] = __hip_atomic_load(&ws[WS_AB + (v << 9) + (h << 6) + c],
                                               __ATOMIC_RELAXED, __HIP_MEMORY_SCOPE_AGENT);
        }
        __syncthreads();
        if (tid < 64) {
            const int a = tid >> 3, b2 = tid & 7;
            float acc = 0.f;
            #pragma unroll
            for (int c = 0; c < 64; ++c)
                acc = fmaf(U.p2.abh[a][c], U.p2.abh[8 + b2][c], acc);
            __hip_atomic_store(&ws[WS_T + (h << 6) + tid], acc * 0.125f,
                               __ATOMIC_RELAXED, __HIP_MEMORY_SCOPE_AGENT);
        } else if (tid < 72) {
            const int a = tid - 64;
            float acc = 0.f;
            #pragma unroll
            for (int c = 0; c < 64; ++c)
                acc = fmaf(U.p2.abh[16 + a][c], Wo[(h << 6) + c], acc);
            __hip_atomic_store(&ws[WS_T + 512 + (h << 3) + a], acc,
                               __ATOMIC_RELAXED, __HIP_MEMORY_SCOPE_AGENT);
        }
        asm volatile("s_waitcnt vmcnt(0)" ::: "memory");
        __syncthreads();
        if (tid == 0)
            __hip_atomic_fetch_add(cnt2, 1, __ATOMIC_RELAXED, __HIP_MEMORY_SCOPE_AGENT);
    }

    // ---------- all blocks: wait for tables, stage T (576 floats) ----------
    if (tid == 0) {
        while (__hip_atomic_load(cnt2, __ATOMIC_RELAXED, __HIP_MEMORY_SCOPE_AGENT) < 8)
            __builtin_amdgcn_s_sleep(1);
    }
    __syncthreads();
    asm volatile("" ::: "memory");
    for (int e = tid; e < 576; e += 256)
        T_s[e] = __hip_atomic_load(&ws[WS_T + e], __ATOMIC_RELAXED, __HIP_MEMORY_SCOPE_AGENT);
    __syncthreads();

    // ---------- phase 3: main attention, grid-stride x2 ----------
    const float vw = stats_s[0];
    const float* cov = stats_s + 1;
    const float* vc = stats_s + 7;
    const float bo0 = bo[0];
    const float* D8 = T_s;
    const float* VD = T_s + 512;

    for (int it = 0; it < 2; ++it) {
        const int g = (it * NBLK + bid) * 256 + tid;
        if (g >= total) break;
        const unsigned b = (unsigned)g / 6u;
        const int i = g - (int)b * 6;

        const float2* xp = (const float2*)(x + (size_t)b * 6u);
        const float2 x01 = xp[0], x23 = xp[1], x45 = xp[2];
        const float al[6] = {x01.x, x01.y, x23.x, x23.y, x45.x, x45.y};

        float r[6], u[6];
        #pragma unroll
        for (int j = 0; j < 6; ++j) {
            float a = al[j];
            float var = fmaf(a, fmaf(a, vw, 2.0f * cov[j]), vc[j]) + 1e-5f;
            r[j] = rsqrtf(var);
            u[j] = a * r[j];
        }

        float bias[6];
        #pragma unroll
        for (int j = 0; j < 6; ++j) bias[j] = FREQ_BIAS[i * 6 + j];

        const float r_i = r[i], u_i = u[i];
        float acc = 0.f;
        float am[6] = {0.f, 0.f, 0.f, 0.f, 0.f, 0.f};

        #pragma unroll
        for (int h = 0; h < 8; ++h) {
            const float* Dh = D8 + h * 64;
            const float* Vh = VD + h * 8;
            const float P1 = Dh[0], P5 = Dh[7], P7 = Dh[56], P9 = Dh[63];
            const float P3i = Dh[(1 + i) * 8], P6i = Dh[(1 + i) * 8 + 7];

            float s[6];
            #pragma unroll
            for (int j = 0; j < 6; ++j) {
                float t1 = fmaf(u[j], P1, fmaf(r[j], Dh[1 + j], P5));
                float t2 = fmaf(u[j], P3i, fmaf(r[j], Dh[(1 + i) * 8 + 1 + j], P6i));
                float t3 = fmaf(u[j], P7, fmaf(r[j], Dh[57 + j], P9));
                s[j] = fmaf(u_i, t1, fmaf(r_i, t2, t3)) + bias[j];
            }
            float m = s[0];
            #pragma unroll
            for (int j = 1; j < 6; ++j) m = fmaxf(m, s[j]);
            float e[6], ssum = 0.f;
            #pragma unroll
            for (int j = 0; j < 6; ++j) { e[j] = __expf(s[j] - m); ssum += e[j]; }
            const float inv = 1.0f / ssum;

            const float av = Vh[0], cvv = Vh[7];
            float ha = 0.f;
            #pragma unroll
            for (int j = 0; j < 6; ++j) {
                float a = e[j] * inv;
                am[j] += a;
                float vp = fmaf(u[j], av, r[j] * Vh[1 + j]);
                ha = fmaf(a, vp, ha);
            }
            acc += ha + cvv;
        }

        out[g] = acc + bo0 + al[i];

        float2* amp = (float2*)(out + total + (size_t)g * 6u);
        amp[0] = make_float2(am[0] * 0.125f, am[1] * 0.125f);
        amp[1] = make_float2(am[2] * 0.125f, am[3] * 0.125f);
        amp[2] = make_float2(am[4] * 0.125f, am[5] * 0.125f);
    }
}

extern "C" void kernel_launch(void* const* d_in, const int* in_sizes, int n_in,
                              void* d_out, int out_size, void* d_ws, size_t ws_size,
                              hipStream_t stream) {
    const float* x     = (const float*)d_in[0];
    const float* W_in  = (const float*)d_in[1];
    const float* b_in  = (const float*)d_in[2];
    const float* Wq    = (const float*)d_in[3];
    const float* bq    = (const float*)d_in[4];
    const float* Wk    = (const float*)d_in[5];
    const float* bk    = (const float*)d_in[6];
    const float* Wv    = (const float*)d_in[7];
    const float* bv    = (const float*)d_in[8];
    const float* Wo    = (const float*)d_in[9];
    const float* bo    = (const float*)d_in[10];
    const float* gamma = (const float*)d_in[11];
    const float* beta  = (const float*)d_in[12];
    float* ws  = (float*)d_ws;
    float* out = (float*)d_out;

    const int total = in_sizes[0];  // B*6

    // zero the atomic-accumulation region + both counters (graph-safe)
    hipMemsetAsync(ws, 0, (WS_CNT2 + 1) * sizeof(float), stream);
    kfused<<<NBLK, 256, 0, stream>>>(x, W_in, b_in, Wq, bq, Wk, bk, Wv, bv,
                                     Wo, bo, gamma, beta, ws, out, total);
}

// Round 6
// 20.634 us; speedup vs baseline: 3.6311x; 1.8175x over previous
//
#include <hip/hip_runtime.h>
#include <math.h>

// ws float layout (tiny): stats + tables only
#define WS_STATS 0     // 13 floats: vw, cov[6], vc[6]
#define WS_T     16    // 577 floats: D8[8*64] | VD[8*8]
// matvec partials (24 stripes x 8 rc x 512 = 98304 floats) live in d_out[0..98303],
// which kC fully overwrites afterwards.

__constant__ float FREQ_BIAS[36] = {
    0.0f, 0.05f, 0.0f, 0.0f, 0.0f, 0.0f,
    0.05f, 0.0f, 0.1f, 0.05f, 0.0f, 0.0f,
    0.0f, 0.1f, 0.0f, 0.1f, 0.0f, 0.0f,
    0.0f, 0.05f, 0.1f, 0.0f, 0.1f, 0.0f,
    0.0f, 0.0f, 0.0f, 0.1f, 0.0f, 0.1f,
    0.0f, 0.0f, 0.0f, 0.0f, 0.1f, 0.0f
};

// kA: LN-fold + matvec partials. 192 blocks (p,cg,rc) x 256 threads.
__global__ __launch_bounds__(256) void kA(
    const float* __restrict__ W_in, const float* __restrict__ b_in,
    const float* __restrict__ gamma, const float* __restrict__ beta,
    const float* __restrict__ Wq, const float* __restrict__ bq,
    const float* __restrict__ Wk, const float* __restrict__ bk,
    const float* __restrict__ Wv, const float* __restrict__ bv,
    float* __restrict__ ws, float* __restrict__ part)
{
    __shared__ float ls[8][512];        // folded vectors: gw, gc0..5, beta
    __shared__ float partial[4][8][64]; // [wave][vec][col]
    __shared__ float red[13][4];

    const int tid = threadIdx.x, wave = tid >> 6, lane = tid & 63;
    const int bid = blockIdx.x;
    const int rc = bid & 7, cg = (bid >> 3) & 7, p = bid >> 6;

    // ---- phase 0: PE + LN stats (HW transcendentals) ----
    const float k_ln = 0.0179889457300305367f;  // ln(10000)/512
    const float freqs[6] = {0.2f, 0.4f, 0.6f, 0.8f, 1.0f, 0.0f};
    float wd[2], cc2[2][6], gm[2], bt[2];
    #pragma unroll
    for (int q = 0; q < 2; ++q) {
        const int d = tid + q * 256;
        wd[q] = W_in[d];
        gm[q] = gamma[d];
        bt[q] = beta[d];
        float dv = __expf(-(float)(d & ~1) * k_ln);
        float bi = b_in[d];
        bool odd = (d & 1);
        #pragma unroll
        for (int s = 0; s < 6; ++s) {
            float ph = freqs[s] * dv;
            cc2[q][s] = bi + (odd ? __cosf(ph) : __sinf(ph));
        }
    }
    {   // means of w and c_s
        float sums[7];
        sums[0] = wd[0] + wd[1];
        #pragma unroll
        for (int s = 0; s < 6; ++s) sums[1 + s] = cc2[0][s] + cc2[1][s];
        #pragma unroll
        for (int m = 1; m < 64; m <<= 1) {
            #pragma unroll
            for (int k = 0; k < 7; ++k) sums[k] += __shfl_xor(sums[k], m, 64);
        }
        if (lane == 0) {
            #pragma unroll
            for (int k = 0; k < 7; ++k) red[k][wave] = sums[k];
        }
    }
    __syncthreads();
    const float mw = (red[0][0] + red[0][1] + red[0][2] + red[0][3]) * (1.0f / 512.0f);
    float mc[6];
    #pragma unroll
    for (int s = 0; s < 6; ++s)
        mc[s] = (red[1 + s][0] + red[1 + s][1] + red[1 + s][2] + red[1 + s][3]) * (1.0f / 512.0f);
    __syncthreads();

    float hw[2], hc[2][6];
    #pragma unroll
    for (int q = 0; q < 2; ++q) {
        hw[q] = wd[q] - mw;
        #pragma unroll
        for (int s = 0; s < 6; ++s) hc[q][s] = cc2[q][s] - mc[s];
    }

    // moments/stats: block 0 only (consumed by kC)
    if (bid == 0) {
        float moms[13];
        moms[0] = hw[0] * hw[0] + hw[1] * hw[1];
        #pragma unroll
        for (int s = 0; s < 6; ++s) {
            moms[1 + s] = hw[0] * hc[0][s] + hw[1] * hc[1][s];
            moms[7 + s] = hc[0][s] * hc[0][s] + hc[1][s] * hc[1][s];
        }
        #pragma unroll
        for (int m = 1; m < 64; m <<= 1) {
            #pragma unroll
            for (int k = 0; k < 13; ++k) moms[k] += __shfl_xor(moms[k], m, 64);
        }
        if (lane == 0) {
            #pragma unroll
            for (int k = 0; k < 13; ++k) red[k][wave] = moms[k];
        }
    }
    // folded vectors
    #pragma unroll
    for (int q = 0; q < 2; ++q) {
        const int d = tid + q * 256;
        ls[0][d] = hw[q] * gm[q];
        #pragma unroll
        for (int s = 0; s < 6; ++s) ls[1 + s][d] = hc[q][s] * gm[q];
        ls[7][d] = bt[q];
    }
    __syncthreads();
    if (bid == 0 && tid < 13)
        ws[WS_STATS + tid] = (red[tid][0] + red[tid][1] + red[tid][2] + red[tid][3]) * (1.0f / 512.0f);

    // ---- matvec: 64-row chunk x 64-col stripe; wave handles 16 rows ----
    const float* W  = (p == 0) ? Wq : ((p == 1) ? Wk : Wv);
    const float* bb = (p == 0) ? bq : ((p == 1) ? bk : bv);
    const int col = (cg << 6) | lane;
    const int row0 = (rc << 6) | (wave << 4);
    float acc[8] = {0.f, 0.f, 0.f, 0.f, 0.f, 0.f, 0.f, 0.f};
    #pragma unroll
    for (int rr = 0; rr < 16; ++rr) {
        const float wv = W[(row0 + rr) * 512 + col];
        #pragma unroll
        for (int v = 0; v < 8; ++v) acc[v] = fmaf(wv, ls[v][row0 + rr], acc[v]);
    }
    #pragma unroll
    for (int v = 0; v < 8; ++v) partial[wave][v][lane] = acc[v];
    __syncthreads();
    #pragma unroll
    for (int ii = 0; ii < 2; ++ii) {
        const int idx = tid + ii * 256;
        const int v = idx >> 6, cx = idx & 63;
        float t = partial[0][v][cx] + partial[1][v][cx]
                + partial[2][v][cx] + partial[3][v][cx];
        if (v == 7 && rc == 0) t += bb[(cg << 6) | cx];
        part[(size_t)bid * 512 + idx] = t;   // [p][cg][rc][v][c], coalesced
    }
}

// kB: reduce partials + dot tables. 8 blocks (one per head) x 256 threads.
__global__ __launch_bounds__(256) void kB(const float* __restrict__ part,
                                          const float* __restrict__ Wo,
                                          float* __restrict__ ws)
{
    __shared__ float ab[24][65];   // padded: vp = p*8+v
    const int tid = threadIdx.x;
    const int h = blockIdx.x;

    for (int e = tid; e < 24 * 64; e += 256) {
        const int vp = e >> 6, c = e & 63;
        const int p = vp >> 3, v = vp & 7;
        const int stripe = p * 8 + h;
        float t = 0.f;
        #pragma unroll
        for (int rcx = 0; rcx < 8; ++rcx)
            t += part[(size_t)(stripe * 8 + rcx) * 512 + v * 64 + c];
        ab[vp][c] = t;
    }
    __syncthreads();

    if (tid < 64) {
        const int a = tid >> 3, b2 = tid & 7;
        float acc = 0.f;
        #pragma unroll
        for (int c = 0; c < 64; ++c)
            acc = fmaf(ab[a][c], ab[8 + b2][c], acc);
        ws[WS_T + (h << 6) + tid] = acc * 0.125f;   // fold hd^-0.5
    } else if (tid < 72) {
        const int a = tid - 64;
        float acc = 0.f;
        #pragma unroll
        for (int c = 0; c < 64; ++c)
            acc = fmaf(ab[16 + a][c], Wo[(h << 6) + c], acc);
        ws[WS_T + 512 + (h << 3) + a] = acc;
    }
}

// kC: main attention. 384 blocks x 256 threads, one (b,i) per thread.
__global__ __launch_bounds__(256) void kC(const float* __restrict__ x,
                                          const float* __restrict__ ws,
                                          const float* __restrict__ bo,
                                          float* __restrict__ out, int total)
{
    __shared__ float T_s[592];   // D8[512] | VD[64] | stats[13]
    const int tid = threadIdx.x;
    for (int e = tid; e < 589; e += 256)
        T_s[e] = (e < 576) ? ws[WS_T + e] : ws[WS_STATS + (e - 576)];
    __syncthreads();

    const int g = blockIdx.x * 256 + tid;
    if (g >= total) return;
    const unsigned b = (unsigned)g / 6u;
    const int i = g - (int)b * 6;

    const float* D8 = T_s;
    const float* VD = T_s + 512;
    const float vw = T_s[576];
    const float* cov = T_s + 577;
    const float* vc = T_s + 583;
    const float bo0 = bo[0];

    const float2* xp = (const float2*)(x + (size_t)b * 6u);
    const float2 x01 = xp[0], x23 = xp[1], x45 = xp[2];
    const float al[6] = {x01.x, x01.y, x23.x, x23.y, x45.x, x45.y};

    float r[6], u[6];
    #pragma unroll
    for (int j = 0; j < 6; ++j) {
        float a = al[j];
        float var = fmaf(a, fmaf(a, vw, 2.0f * cov[j]), vc[j]) + 1e-5f;
        r[j] = rsqrtf(var);
        u[j] = a * r[j];
    }

    float bias[6];
    #pragma unroll
    for (int j = 0; j < 6; ++j) bias[j] = FREQ_BIAS[i * 6 + j];

    const float r_i = r[i], u_i = u[i];
    float acc = 0.f;
    float am[6] = {0.f, 0.f, 0.f, 0.f, 0.f, 0.f};

    #pragma unroll
    for (int h = 0; h < 8; ++h) {
        const float* Dh = D8 + h * 64;
        const float* Vh = VD + h * 8;
        const float P1 = Dh[0], P5 = Dh[7], P7 = Dh[56], P9 = Dh[63];
        const float P3i = Dh[(1 + i) * 8], P6i = Dh[(1 + i) * 8 + 7];

        float s[6];
        #pragma unroll
        for (int j = 0; j < 6; ++j) {
            float t1 = fmaf(u[j], P1, fmaf(r[j], Dh[1 + j], P5));
            float t2 = fmaf(u[j], P3i, fmaf(r[j], Dh[(1 + i) * 8 + 1 + j], P6i));
            float t3 = fmaf(u[j], P7, fmaf(r[j], Dh[57 + j], P9));
            s[j] = fmaf(u_i, t1, fmaf(r_i, t2, t3)) + bias[j];
        }
        float m = s[0];
        #pragma unroll
        for (int j = 1; j < 6; ++j) m = fmaxf(m, s[j]);
        float e[6], ssum = 0.f;
        #pragma unroll
        for (int j = 0; j < 6; ++j) { e[j] = __expf(s[j] - m); ssum += e[j]; }
        const float inv = 1.0f / ssum;

        const float av = Vh[0], cvv = Vh[7];
        float ha = 0.f;
        #pragma unroll
        for (int j = 0; j < 6; ++j) {
            float a = e[j] * inv;
            am[j] += a;
            float vp = fmaf(u[j], av, r[j] * Vh[1 + j]);
            ha = fmaf(a, vp, ha);
        }
        acc += ha + cvv;
    }

    out[g] = acc + bo0 + al[i];

    float2* amp = (float2*)(out + total + (size_t)g * 6u);
    amp[0] = make_float2(am[0] * 0.125f, am[1] * 0.125f);
    amp[1] = make_float2(am[2] * 0.125f, am[3] * 0.125f);
    amp[2] = make_float2(am[4] * 0.125f, am[5] * 0.125f);
}

extern "C" void kernel_launch(void* const* d_in, const int* in_sizes, int n_in,
                              void* d_out, int out_size, void* d_ws, size_t ws_size,
                              hipStream_t stream) {
    const float* x     = (const float*)d_in[0];
    const float* W_in  = (const float*)d_in[1];
    const float* b_in  = (const float*)d_in[2];
    const float* Wq    = (const float*)d_in[3];
    const float* bq    = (const float*)d_in[4];
    const float* Wk    = (const float*)d_in[5];
    const float* bk    = (const float*)d_in[6];
    const float* Wv    = (const float*)d_in[7];
    const float* bv    = (const float*)d_in[8];
    const float* Wo    = (const float*)d_in[9];
    const float* bo    = (const float*)d_in[10];
    const float* gamma = (const float*)d_in[11];
    const float* beta  = (const float*)d_in[12];
    float* ws  = (float*)d_ws;
    float* out = (float*)d_out;

    const int total = in_sizes[0];  // B*6 = 98304

    // partials use out[0..98303] as scratch; kC fully overwrites out.
    kA<<<192, 256, 0, stream>>>(W_in, b_in, gamma, beta, Wq, bq, Wk, bk, Wv, bv, ws, out);
    kB<<<8, 256, 0, stream>>>(out, Wo, ws);
    kC<<<(total + 255) / 256, 256, 0, stream>>>(x, ws, bo, out, total);
}